// Round 7
// baseline (232.873 us; speedup 1.0000x reference)
//
#include <hip/hip_runtime.h>
#include <hip/hip_bf16.h>
#include <stdint.h>

#define T_STEPS 64
#define B_SZ 8
#define C_DIM 64
#define V_SZ 16000
#define K_DIM 4096   // C*C
#define M_ROWS 512   // T*B
#define BM 128
#define BN 128
#define BK 32
#define NITER (K_DIM / BK)  // 128
#define NWG ((M_ROWS / BM) * (V_SZ / BN))  // 500
#define WBYTES 16384  // 128 cols x 32 k x 4B, XOR-swizzled

typedef __bf16 bf16x8 __attribute__((ext_vector_type(8)));
typedef float f32x4 __attribute__((ext_vector_type(4)));

__device__ __forceinline__ void gll16(const void* g, void* l) {
  __builtin_amdgcn_global_load_lds(
      (const __attribute__((address_space(1))) void*)g,
      (__attribute__((address_space(3))) void*)l, 16, 0, 0);
}

// ---------------- Kernel 1: sequential ctx recurrence ----------------
__global__ void ctx_kernel(const int* __restrict__ tokens,
                           const float* __restrict__ emb_ctx,
                           const float* __restrict__ beta_mult,
                           const float* __restrict__ beta_power,
                           float* __restrict__ ctx_hist) {
  const int b = blockIdx.x;
  const int d = threadIdx.x;
  const float bm = beta_mult[0];
  const float bp = beta_power[0];
  float ctx = 0.0f;
  for (int t = 0; t < T_STEPS; ++t) {
    const int tok = tokens[t * B_SZ + b];
    const float ce = emb_ctx[tok * C_DIM + d];
    float ne2 = ce * ce;
    float c2 = ctx * ctx;
#pragma unroll
    for (int s = 32; s > 0; s >>= 1) {
      ne2 += __shfl_xor(ne2, s, 64);
      c2 += __shfl_xor(c2, s, 64);
    }
    const float ne = sqrtf(ne2);
    const float nc = sqrtf(c2);
    float beta = powf(bm * (ne / (ne + nc)), bp);  // ALPHA == 1
    beta = fminf(fmaxf(beta, 0.0f), 1.0f);
    ctx = (1.0f - beta) * ctx + beta * ce;
    ctx_hist[(t * B_SZ + b) * C_DIM + d] = ctx;
  }
}

// ---------------- Kernel 2: fused GEMM, A built in registers ------------------
// out[512,16000] = M * W^T with M[m, c*64+d] = ae[m][c]*ctx[m][d].
// Per BK=32 tile kt: c = kt>>1 constant; d-half = kt&1.
// A-frag (row, k=g*8+j) = ae[row][c] * ctx[row][(kt&1)*32 + g*8 + j]:
// ctx bf16 frags VGPR-resident (loaded once), ae in 16KB bf16 LDS [c][m].
// => ZERO A memory traffic in the K-loop (was 524 MB device-wide = the R6 bound).
// W path = R6's proven pipeline: gll16 -> 3-buf LDS (48KB), depth-2 prefetch,
// counted vmcnt(8), 2 raw barriers/iter, never vmcnt(0) in the loop.
// Waves 1x4: each wave owns 128M x 32N -> each W element read by exactly 1 wave.
// XCD swizzle (m204) keeps the 4 same-W-panel blocks L2-siblings.
__global__ __launch_bounds__(256, 2)
void gemm_kernel(const int* __restrict__ tokens,
                 const float* __restrict__ emb_act,
                 const float* __restrict__ ctx_hist,
                 const float* __restrict__ W,
                 float* __restrict__ out) {
  __shared__ __align__(16) char wsm[3][WBYTES];  // 48 KB
  __shared__ __bf16 aeb[C_DIM][BM];              // 16 KB, [c][m]

  const int tid = threadIdx.x;
  const int lane = tid & 63;
  const int w = tid >> 6;
  const int lrow = lane & 15;
  const int g = lane >> 4;

  const int orig = blockIdx.x;
  const int xcd = orig & 7;
  const int wg = ((xcd < 4) ? xcd * 63 : 252 + (xcd - 4) * 62) + (orig >> 3);
  const int m0 = (wg & 3) * BM;
  const int n0 = (wg >> 2) * BN;

  // ---- prologue: ae gather -> bf16 LDS [c][m] ----
  {
    const int m = tid & 127;
    const int c0 = (tid >> 7) * 32;
    const int tok = tokens[m0 + m];
    const float* ap = emb_act + (size_t)tok * C_DIM + c0;
#pragma unroll
    for (int i = 0; i < 32; ++i) aeb[c0 + i][m] = (__bf16)ap[i];
  }

  // ---- prologue: ctx frags -> registers (bf16). row = fm*16+lrow ----
  bf16x8 ctxr[8][2];
#pragma unroll
  for (int fm = 0; fm < 8; ++fm)
#pragma unroll
    for (int h = 0; h < 2; ++h) {
      const float* cp =
          ctx_hist + (size_t)(m0 + fm * 16 + lrow) * C_DIM + h * 32 + g * 8;
      const f32x4 c0 = *(const f32x4*)cp;
      const f32x4 c1 = *(const f32x4*)(cp + 4);
      bf16x8 v;
#pragma unroll
      for (int j = 0; j < 4; ++j) {
        v[j] = (__bf16)c0[j];
        v[4 + j] = (__bf16)c1[j];
      }
      ctxr[fm][h] = v;
    }

  // ---- W staging (R6 verbatim, minus A): pre-swizzled source, linear dest ----
  const char* const Wc = (const char*)W;
  const int woff = ((tid & 7) * 16) ^ (((tid >> 3) & 7) << 4);
  const char* wbase[4];
#pragma unroll
  for (int s = 0; s < 4; ++s)
    wbase[s] = Wc + (size_t)(n0 + s * 32 + (tid >> 3)) * (K_DIM * 4) + woff;

  auto STAGE = [&](int b, int kt) {
    char* dst = wsm[b];
#pragma unroll
    for (int s = 0; s < 4; ++s)
      gll16(wbase[s] + (size_t)kt * 128, dst + s * 4096 + tid * 16);
  };

  __syncthreads();  // aeb ready

  STAGE(0, 0);
  STAGE(1, 1);

  f32x4 acc[8][2];
#pragma unroll
  for (int fm = 0; fm < 8; ++fm)
#pragma unroll
    for (int fn = 0; fn < 2; ++fn) acc[fm][fn] = (f32x4){0.f, 0.f, 0.f, 0.f};

  float aev[8];

  // one K-step: stage kt+2 (unless tail), A-build in regs, counted wait, MFMA
  auto KSTEP = [&](int kt, int u, int cur, int vm) {
    if (vm == 8) STAGE((cur == 0) ? 2 : cur - 1, kt + 2);
    if (u == 0) {  // c changed
      const int c = kt >> 1;
#pragma unroll
      for (int fm = 0; fm < 8; ++fm)
        aev[fm] = (float)aeb[c][fm * 16 + lrow];
    }
    if (vm == 8)
      asm volatile("s_waitcnt vmcnt(8)" ::: "memory");
    else if (vm == 4)
      asm volatile("s_waitcnt vmcnt(4)" ::: "memory");
    else
      asm volatile("s_waitcnt vmcnt(0)" ::: "memory");
    __builtin_amdgcn_s_barrier();
    // W frags (bf16-cvt) for this wave's 32 cols
    const char* Wb = wsm[cur];
    bf16x8 bv[2];
#pragma unroll
    for (int fn = 0; fn < 2; ++fn) {
      const int col = w * 32 + fn * 16 + lrow;
      const int xo = (col & 7) << 4;
      const f32x4 b0 = *(const f32x4*)(Wb + col * 128 + ((g * 32) ^ xo));
      const f32x4 b1 = *(const f32x4*)(Wb + col * 128 + ((g * 32 + 16) ^ xo));
#pragma unroll
      for (int j = 0; j < 4; ++j) {
        bv[fn][j] = (__bf16)b0[j];
        bv[fn][4 + j] = (__bf16)b1[j];
      }
    }
    // A-build + MFMA, af transient per fm
#pragma unroll
    for (int fm = 0; fm < 8; ++fm) {
      const float av = aev[fm];
      const bf16x8 cx = ctxr[fm][u];
      bf16x8 af;
#pragma unroll
      for (int j = 0; j < 8; ++j) af[j] = (__bf16)(av * (float)cx[j]);
      acc[fm][0] =
          __builtin_amdgcn_mfma_f32_16x16x32_bf16(af, bv[0], acc[fm][0], 0, 0, 0);
      acc[fm][1] =
          __builtin_amdgcn_mfma_f32_16x16x32_bf16(af, bv[1], acc[fm][1], 0, 0, 0);
    }
    __builtin_amdgcn_s_barrier();
  };

  int cur = 0;
#pragma unroll 1
  for (int p = 0; p < NITER / 2 - 1; ++p) {
#pragma unroll
    for (int u = 0; u < 2; ++u) {
      KSTEP(2 * p + u, u, cur, 8);
      cur = (cur == 2) ? 0 : cur + 1;
    }
  }
  KSTEP(NITER - 2, 0, cur, 4);
  cur = (cur == 2) ? 0 : cur + 1;
  KSTEP(NITER - 1, 1, cur, 0);

  // ---- epilogue: C/D layout col = lane&15, row = (lane>>4)*4 + q ----
#pragma unroll
  for (int fm = 0; fm < 8; ++fm)
#pragma unroll
    for (int q = 0; q < 4; ++q) {
      const int row = m0 + fm * 16 + g * 4 + q;
      float* po = out + (size_t)row * V_SZ + n0 + w * 32 + lrow;
#pragma unroll
      for (int fn = 0; fn < 2; ++fn) po[fn * 16] = acc[fm][fn][q];
    }
}

extern "C" void kernel_launch(void* const* d_in, const int* in_sizes, int n_in,
                              void* d_out, int out_size, void* d_ws, size_t ws_size,
                              hipStream_t stream) {
  const int* tokens = (const int*)d_in[0];
  const float* emb_ctx = (const float*)d_in[1];
  const float* emb_act = (const float*)d_in[2];
  const float* W = (const float*)d_in[3];
  const float* beta_mult = (const float*)d_in[4];
  const float* beta_power = (const float*)d_in[5];
  float* out = (float*)d_out;

  float* ctx_hist = (float*)d_ws;  // 128 KB

  ctx_kernel<<<B_SZ, C_DIM, 0, stream>>>(tokens, emb_ctx, beta_mult, beta_power,
                                         ctx_hist);
  gemm_kernel<<<NWG, 256, 0, stream>>>(tokens, emb_act, ctx_hist, W, out);
}

// Round 8
// 224.459 us; speedup vs baseline: 1.0375x; 1.0375x over previous
//
#include <hip/hip_runtime.h>
#include <hip/hip_bf16.h>
#include <stdint.h>

#define T_STEPS 64
#define B_SZ 8
#define C_DIM 64
#define V_SZ 16000
#define K_DIM 4096   // C*C
#define M_ROWS 512   // T*B
#define BM 128
#define BN 128
#define NWG ((M_ROWS / BM) * (V_SZ / BN))  // 500

typedef __bf16 bf16x8 __attribute__((ext_vector_type(8)));
typedef float f32x4 __attribute__((ext_vector_type(4)));

// ---------------- Kernel 1: sequential ctx recurrence ----------------
__global__ void ctx_kernel(const int* __restrict__ tokens,
                           const float* __restrict__ emb_ctx,
                           const float* __restrict__ beta_mult,
                           const float* __restrict__ beta_power,
                           float* __restrict__ ctx_hist) {
  const int b = blockIdx.x;
  const int d = threadIdx.x;
  const float bm = beta_mult[0];
  const float bp = beta_power[0];
  float ctx = 0.0f;
  for (int t = 0; t < T_STEPS; ++t) {
    const int tok = tokens[t * B_SZ + b];
    const float ce = emb_ctx[tok * C_DIM + d];
    float ne2 = ce * ce;
    float c2 = ctx * ctx;
#pragma unroll
    for (int s = 32; s > 0; s >>= 1) {
      ne2 += __shfl_xor(ne2, s, 64);
      c2 += __shfl_xor(c2, s, 64);
    }
    const float ne = sqrtf(ne2);
    const float nc = sqrtf(c2);
    float beta = powf(bm * (ne / (ne + nc)), bp);  // ALPHA == 1
    beta = fminf(fmaxf(beta, 0.0f), 1.0f);
    ctx = (1.0f - beta) * ctx + beta * ce;
    ctx_hist[(t * B_SZ + b) * C_DIM + d] = ctx;
  }
}

// ---------------- Kernel 2: fused GEMM, ae-scale on the ACCUMULATOR -----------
// out[m, v] = sum_c ae[m,c] * P_c[m,v],  P_c[m,v] = sum_d ctx[m,d] * W[v, c*64+d].
// Per c-step: A-operand = VGPR-resident ctx frags (identical every step -> no
// per-iter A-build, no A memory traffic); two chained K=32 MFMAs -> P (f32);
// acc += ae (x) P with ae indexed by OUTPUT rows (g*4+q), one ds_read_b128
// per fm from the [c][m] f32 LDS table (broadcast across lrow, conflict-free).
// W: wave-private 32 cols, direct global->VGPR f32x4 of exactly the needed
// frag bytes; depth-1 prefetch into reused regs. ZERO barriers / LDS traffic
// for W in the loop -> waves fully decoupled; latency hidden by 2 waves/SIMD
// + one-compute-phase prefetch distance (enough for L3-resident W).
// XCD swizzle (m204 bijective) keeps the 4 blocks sharing a W panel L2-siblings.
__global__ __launch_bounds__(256, 2)
void gemm_kernel(const int* __restrict__ tokens,
                 const float* __restrict__ emb_act,
                 const float* __restrict__ ctx_hist,
                 const float* __restrict__ W,
                 float* __restrict__ out) {
  __shared__ float aeb[C_DIM][BM];  // 32 KB, [c][m] f32

  const int tid = threadIdx.x;
  const int lane = tid & 63;
  const int w = tid >> 6;
  const int lrow = lane & 15;
  const int g = lane >> 4;

  const int orig = blockIdx.x;
  const int xcd = orig & 7;
  const int wg = ((xcd < 4) ? xcd * 63 : 252 + (xcd - 4) * 62) + (orig >> 3);
  const int m0 = (wg & 3) * BM;
  const int n0 = (wg >> 2) * BN;

  // ---- prologue: ae -> f32 LDS [c][m] ----
  {
    const int m = tid & 127;
    const int c0 = (tid >> 7) * 32;
    const int tok = tokens[m0 + m];
    const float* ap = emb_act + (size_t)tok * C_DIM + c0;
#pragma unroll
    for (int i = 0; i < 32; ++i) aeb[c0 + i][m] = ap[i];
  }

  // ---- prologue: ctx frags -> registers (bf16), reused all 64 c-steps ----
  // ctxr[fm][half] = ctx[m0+fm*16+lrow][half*32 + g*8 + j]
  bf16x8 ctxr[8][2];
#pragma unroll
  for (int fm = 0; fm < 8; ++fm)
#pragma unroll
    for (int h = 0; h < 2; ++h) {
      const float* cp =
          ctx_hist + (size_t)(m0 + fm * 16 + lrow) * C_DIM + h * 32 + g * 8;
      const f32x4 c0 = *(const f32x4*)cp;
      const f32x4 c1 = *(const f32x4*)(cp + 4);
      bf16x8 v;
#pragma unroll
      for (int j = 0; j < 4; ++j) {
        v[j] = (__bf16)c0[j];
        v[4 + j] = (__bf16)c1[j];
      }
      ctxr[fm][h] = v;
    }

  __syncthreads();  // aeb ready; only block-wide sync

  // ---- W pointers: lane (lrow,g) loads exactly its frag bytes ----
  // bv[fn][half] needs W[n0 + w*32 + fn*16 + lrow][c*64 + half*32 + g*8 .. +7]
  const float* wb[2];
  wb[0] = W + (size_t)(n0 + w * 32 + lrow) * K_DIM + g * 8;
  wb[1] = wb[0] + (size_t)16 * K_DIM;

  f32x4 wbuf[2][2][2];  // [fn][half][piece], reused each step (static idx)
#pragma unroll
  for (int fn = 0; fn < 2; ++fn)
#pragma unroll
    for (int h = 0; h < 2; ++h)
#pragma unroll
      for (int pc = 0; pc < 2; ++pc)
        wbuf[fn][h][pc] = *(const f32x4*)(wb[fn] + h * 32 + pc * 4);

  f32x4 acc[8][2];
#pragma unroll
  for (int fm = 0; fm < 8; ++fm)
#pragma unroll
    for (int fn = 0; fn < 2; ++fn) acc[fm][fn] = (f32x4){0.f, 0.f, 0.f, 0.f};

  const f32x4 zed = (f32x4){0.f, 0.f, 0.f, 0.f};

#pragma unroll 1
  for (int c = 0; c < C_DIM; ++c) {
    // 1. ae rows for the OUTPUT tile: aev[fm][q] = ae[m0+fm*16+g*4+q][c]
    f32x4 aev[8];
#pragma unroll
    for (int fm = 0; fm < 8; ++fm)
      aev[fm] = *(const f32x4*)&aeb[c][fm * 16 + g * 4];
    // 2. cvt current W regs -> bf16 frags (waits on last step's loads)
    bf16x8 bv[2][2];
#pragma unroll
    for (int fn = 0; fn < 2; ++fn)
#pragma unroll
      for (int h = 0; h < 2; ++h) {
#pragma unroll
        for (int j = 0; j < 4; ++j) {
          bv[fn][h][j] = (__bf16)wbuf[fn][h][0][j];
          bv[fn][h][4 + j] = (__bf16)wbuf[fn][h][1][j];
        }
      }
    // 3. prefetch c+1 into the freed regs (clamped re-read on last step)
    {
      const int cn = (c + 1 < C_DIM) ? c + 1 : c;
#pragma unroll
      for (int fn = 0; fn < 2; ++fn)
#pragma unroll
        for (int h = 0; h < 2; ++h)
#pragma unroll
          for (int pc = 0; pc < 2; ++pc)
            wbuf[fn][h][pc] =
                *(const f32x4*)(wb[fn] + cn * 64 + h * 32 + pc * 4);
    }
    // 4. P_c via chained MFMA, then accumulator-side ae-scale
#pragma unroll
    for (int fm = 0; fm < 8; ++fm) {
#pragma unroll
      for (int fn = 0; fn < 2; ++fn) {
        f32x4 p = __builtin_amdgcn_mfma_f32_16x16x32_bf16(ctxr[fm][0],
                                                          bv[fn][0], zed, 0, 0, 0);
        p = __builtin_amdgcn_mfma_f32_16x16x32_bf16(ctxr[fm][1], bv[fn][1], p,
                                                    0, 0, 0);
        acc[fm][fn] += aev[fm] * p;
      }
    }
  }

  // ---- epilogue: C/D layout col = lane&15, row = (lane>>4)*4 + q ----
#pragma unroll
  for (int fm = 0; fm < 8; ++fm)
#pragma unroll
    for (int q = 0; q < 4; ++q) {
      const int row = m0 + fm * 16 + g * 4 + q;
      float* po = out + (size_t)row * V_SZ + n0 + w * 32 + lrow;
#pragma unroll
      for (int fn = 0; fn < 2; ++fn) po[fn * 16] = acc[fm][fn][q];
    }
}

extern "C" void kernel_launch(void* const* d_in, const int* in_sizes, int n_in,
                              void* d_out, int out_size, void* d_ws, size_t ws_size,
                              hipStream_t stream) {
  const int* tokens = (const int*)d_in[0];
  const float* emb_ctx = (const float*)d_in[1];
  const float* emb_act = (const float*)d_in[2];
  const float* W = (const float*)d_in[3];
  const float* beta_mult = (const float*)d_in[4];
  const float* beta_power = (const float*)d_in[5];
  float* out = (float*)d_out;

  float* ctx_hist = (float*)d_ws;  // 128 KB

  ctx_kernel<<<B_SZ, C_DIM, 0, stream>>>(tokens, emb_ctx, beta_mult, beta_power,
                                         ctx_hist);
  gemm_kernel<<<NWG, 256, 0, stream>>>(tokens, emb_act, ctx_hist, W, out);
}

// Round 9
// 219.763 us; speedup vs baseline: 1.0597x; 1.0214x over previous
//
#include <hip/hip_runtime.h>
#include <hip/hip_bf16.h>
#include <stdint.h>

#define T_STEPS 64
#define B_SZ 8
#define C_DIM 64
#define V_SZ 16000
#define K_DIM 4096   // C*C
#define M_ROWS 512   // T*B
#define BM 128
#define BN 64
#define BK 32
#define NITER (K_DIM / BK)  // 128
#define NWG ((M_ROWS / BM) * (V_SZ / BN))  // 4 * 250 = 1000
#define ABYTES 8192          // 128 rows x 32 k bf16, [g][row][16B] ^ (g<<5)
#define WBYTES 8192          // 64 cols x 32 k f32, [col][128B] ^ ((col&7)<<4)
#define BUFBYTES (ABYTES + WBYTES)  // 16384

typedef __bf16 bf16x8 __attribute__((ext_vector_type(8)));
typedef float f32x4 __attribute__((ext_vector_type(4)));

__device__ __forceinline__ void gll16(const void* g, void* l) {
  __builtin_amdgcn_global_load_lds(
      (const __attribute__((address_space(1))) void*)g,
      (__attribute__((address_space(3))) void*)l, 16, 0, 0);
}

// ---------------- Kernel 1: sequential ctx recurrence ----------------
__global__ void ctx_kernel(const int* __restrict__ tokens,
                           const float* __restrict__ emb_ctx,
                           const float* __restrict__ beta_mult,
                           const float* __restrict__ beta_power,
                           float* __restrict__ ctx_hist) {
  const int b = blockIdx.x;
  const int d = threadIdx.x;
  const float bm = beta_mult[0];
  const float bp = beta_power[0];
  float ctx = 0.0f;
  for (int t = 0; t < T_STEPS; ++t) {
    const int tok = tokens[t * B_SZ + b];
    const float ce = emb_ctx[tok * C_DIM + d];
    float ne2 = ce * ce;
    float c2 = ctx * ctx;
#pragma unroll
    for (int s = 32; s > 0; s >>= 1) {
      ne2 += __shfl_xor(ne2, s, 64);
      c2 += __shfl_xor(c2, s, 64);
    }
    const float ne = sqrtf(ne2);
    const float nc = sqrtf(c2);
    float beta = powf(bm * (ne / (ne + nc)), bp);  // ALPHA == 1
    beta = fminf(fmaxf(beta, 0.0f), 1.0f);
    ctx = (1.0f - beta) * ctx + beta * ce;
    ctx_hist[(t * B_SZ + b) * C_DIM + d] = ctx;
  }
}

// ---------------- Kernel 2: build M in MFMA-fragment-blocked layout ----------
// (m,k) -> byte (k>>5)*32768 + ((k>>3)&3)*8192 + m*16 + (k&7)*2.
__global__ void build_m(const int* __restrict__ tokens,
                        const float* __restrict__ emb_act,
                        const float* __restrict__ ctx_hist,
                        char* __restrict__ Mblk) {
  const int m = blockIdx.x;
  const int tid = threadIdx.x;
  __shared__ float ctxs[C_DIM];
  __shared__ float aes[C_DIM];
  const int t = m >> 3, b = m & 7;
  const int tok = tokens[t * B_SZ + b];
  if (tid < C_DIM) {
    ctxs[tid] = ctx_hist[m * C_DIM + tid];
    aes[tid] = emb_act[tok * C_DIM + tid];
  }
  __syncthreads();
  const int c = tid >> 1;
  const int dh = (tid & 1) * 32;
  const float ae = aes[c];
#pragma unroll
  for (int q = 0; q < 4; ++q) {
    const int k0 = c * C_DIM + dh + q * 8;
    bf16x8 v;
#pragma unroll
    for (int jj = 0; jj < 8; ++jj) v[jj] = (__bf16)(ae * ctxs[dh + q * 8 + jj]);
    *(bf16x8*)(void*)(Mblk + (size_t)(k0 >> 5) * 32768 + ((k0 >> 3) & 3) * 8192 +
                      m * 16) = v;
  }
}

// ---------------- Kernel 3: GEMM out[512,16000] = M[512,4096] * W^T ------------
// BM=128 BN=64 BK=32, 4 waves (2x2; each 64M x 32N), grid 1000 -> 4 blocks/CU.
// 2-buffer LDS (32 KB), depth-1 prefetch, counted vmcnt(4), 2 barriers/iter,
// vmcnt never drained in the loop. A LDS: [g][row][16B] XOR (g<<5) -> 2-way
// (free) reads; W LDS: [col][128B] XOR ((col&7)<<4) -> 2-way reads. Both
// swizzles applied inversely on the gll16 SOURCE (linear dest, rule #21).
// XCD swizzle (1000%8==0): same-W-panel blocks are XCD-siblings -> W re-reads
// are L2 hits; W read once from HBM device-wide.
__global__ __launch_bounds__(256, 4)
void gemm_kernel(const char* __restrict__ Ablk, const float* __restrict__ W,
                 float* __restrict__ out) {
  __shared__ __align__(16) char smem[2][BUFBYTES];  // 32 KB
  const int tid = threadIdx.x;
  const int lane = tid & 63;
  const int w = tid >> 6;
  const int wm = w >> 1, wn = w & 1;
  const int lrow = lane & 15;
  const int g = lane >> 4;

  // XCD chunk swizzle (bijective, 1000 % 8 == 0): wg consecutive => same XCD.
  const int wg = (blockIdx.x & 7) * (NWG / 8) + (blockIdx.x >> 3);
  const int m0 = (wg & 3) * BM;        // 4 same-panel blocks are wg-adjacent
  const int n0 = (wg >> 2) * BN;

  // ---- staging sources (pre-swizzled for linear gll16 dests) ----
  // A: logical (ga,row) stored at ga*2048 + (row*16 ^ (ga<<5))
  const char* asrc[2];
#pragma unroll
  for (int s = 0; s < 2; ++s) {
    const int L = s * 4096 + tid * 16;
    const int ga = L >> 11;
    const int row = ((L & 2047) ^ (ga << 5)) >> 4;
    asrc[s] = Ablk + ga * 8192 + (size_t)(m0 + row) * 16;
  }
  // W: logical (col,koff) stored at col*128 + (koff ^ ((col&7)<<4))
  const char* wsrc[2];
#pragma unroll
  for (int s = 0; s < 2; ++s) {
    const int col = s * 32 + (tid >> 3);
    const int koff = ((tid & 7) * 16) ^ ((col & 7) << 4);
    wsrc[s] = (const char*)W + (size_t)(n0 + col) * (K_DIM * 4) + koff;
  }

  auto STAGE = [&](int b, int kt) {
    char* dst = smem[b];
    gll16(asrc[0] + (size_t)kt * 32768, dst + tid * 16);
    gll16(asrc[1] + (size_t)kt * 32768, dst + 4096 + tid * 16);
    gll16(wsrc[0] + (size_t)kt * 128, dst + ABYTES + tid * 16);
    gll16(wsrc[1] + (size_t)kt * 128, dst + ABYTES + 4096 + tid * 16);
  };

  f32x4 acc[4][2];
#pragma unroll
  for (int fm = 0; fm < 4; ++fm)
#pragma unroll
    for (int fn = 0; fn < 2; ++fn) acc[fm][fn] = (f32x4){0.f, 0.f, 0.f, 0.f};

  auto COMPUTE = [&](int b) {
    const char* Ab = smem[b];
    const char* Wb = smem[b] + ABYTES;
    bf16x8 a[4];
#pragma unroll
    for (int fm = 0; fm < 4; ++fm) {
      const int row = wm * 64 + fm * 16 + lrow;
      a[fm] = *(const bf16x8*)(Ab + g * 2048 + ((row * 16) ^ (g << 5)));
    }
#pragma unroll
    for (int fn = 0; fn < 2; ++fn) {
      const int col = wn * 32 + fn * 16 + lrow;
      const int xo = (col & 7) << 4;
      const f32x4 b0 = *(const f32x4*)(Wb + col * 128 + ((g * 32) ^ xo));
      const f32x4 b1 = *(const f32x4*)(Wb + col * 128 + ((g * 32 + 16) ^ xo));
      bf16x8 bv;
#pragma unroll
      for (int j = 0; j < 4; ++j) {
        bv[j] = (__bf16)b0[j];
        bv[4 + j] = (__bf16)b1[j];
      }
#pragma unroll
      for (int fm = 0; fm < 4; ++fm)
        acc[fm][fn] =
            __builtin_amdgcn_mfma_f32_16x16x32_bf16(a[fm], bv, acc[fm][fn], 0, 0, 0);
    }
  };

  STAGE(0, 0);
  int cur = 0;
#pragma unroll 1
  for (int kt = 0; kt < NITER - 1; ++kt) {
    STAGE(cur ^ 1, kt + 1);
    asm volatile("s_waitcnt vmcnt(4)" ::: "memory");  // tile kt's 4 landed
    __builtin_amdgcn_s_barrier();
    COMPUTE(cur);
    __builtin_amdgcn_s_barrier();  // frag reads done before buf overwrite
    cur ^= 1;
  }
  asm volatile("s_waitcnt vmcnt(0)" ::: "memory");
  __builtin_amdgcn_s_barrier();
  COMPUTE(cur);

  // Epilogue: C/D layout col = lane&15, row = (lane>>4)*4 + q.
#pragma unroll
  for (int fm = 0; fm < 4; ++fm)
#pragma unroll
    for (int q = 0; q < 4; ++q) {
      const int row = m0 + wm * 64 + fm * 16 + g * 4 + q;
      float* po = out + (size_t)row * V_SZ + n0 + wn * 32 + lrow;
      po[0] = acc[fm][0][q];
      po[16] = acc[fm][1][q];
    }
}

extern "C" void kernel_launch(void* const* d_in, const int* in_sizes, int n_in,
                              void* d_out, int out_size, void* d_ws, size_t ws_size,
                              hipStream_t stream) {
  const int* tokens = (const int*)d_in[0];
  const float* emb_ctx = (const float*)d_in[1];
  const float* emb_act = (const float*)d_in[2];
  const float* W = (const float*)d_in[3];
  const float* beta_mult = (const float*)d_in[4];
  const float* beta_power = (const float*)d_in[5];
  float* out = (float*)d_out;

  char* Mblk = (char*)d_ws;  // 4 MB, blocked layout
  float* ctx_hist = (float*)((char*)d_ws + (size_t)M_ROWS * K_DIM * 2);  // 128 KB

  ctx_kernel<<<B_SZ, C_DIM, 0, stream>>>(tokens, emb_ctx, beta_mult, beta_power,
                                         ctx_hist);
  build_m<<<M_ROWS, 128, 0, stream>>>(tokens, emb_act, ctx_hist, Mblk);
  gemm_kernel<<<NWG, 256, 0, stream>>>(Mblk, W, out);
}

// Round 11
// 208.725 us; speedup vs baseline: 1.1157x; 1.0529x over previous
//
#include <hip/hip_runtime.h>
#include <hip/hip_bf16.h>
#include <stdint.h>

#define T_STEPS 64
#define B_SZ 8
#define C_DIM 64
#define V_SZ 16000
#define K_DIM 4096   // C*C
#define M_ROWS 512   // T*B
#define BM 256
#define BN 128
#define NPH 128      // K half-tiles of 32
#define NWG ((M_ROWS / BM) * (V_SZ / BN))  // 2 * 125 = 250
#define AH_BYTES 16384  // A half-tile: 256 rows x 64B (plain blocked image)
#define WSLOT 16384     // W half-tile: 128 cols x 128B f32 (XOR-swizzled rows)

typedef __bf16 bf16x8 __attribute__((ext_vector_type(8)));
typedef float f32x4 __attribute__((ext_vector_type(4)));

__device__ __forceinline__ void gll16(const void* g, void* l) {
  __builtin_amdgcn_global_load_lds(
      (const __attribute__((address_space(1))) void*)g,
      (__attribute__((address_space(3))) void*)l, 16, 0, 0);
}

// ---------------- Kernel 1: sequential ctx recurrence ----------------
__global__ void ctx_kernel(const int* __restrict__ tokens,
                           const float* __restrict__ emb_ctx,
                           const float* __restrict__ beta_mult,
                           const float* __restrict__ beta_power,
                           float* __restrict__ ctx_hist) {
  const int b = blockIdx.x;
  const int d = threadIdx.x;
  const float bm = beta_mult[0];
  const float bp = beta_power[0];
  float ctx = 0.0f;
  for (int t = 0; t < T_STEPS; ++t) {
    const int tok = tokens[t * B_SZ + b];
    const float ce = emb_ctx[tok * C_DIM + d];
    float ne2 = ce * ce;
    float c2 = ctx * ctx;
#pragma unroll
    for (int s = 32; s > 0; s >>= 1) {
      ne2 += __shfl_xor(ne2, s, 64);
      c2 += __shfl_xor(c2, s, 64);
    }
    const float ne = sqrtf(ne2);
    const float nc = sqrtf(c2);
    float beta = powf(bm * (ne / (ne + nc)), bp);  // ALPHA == 1
    beta = fminf(fmaxf(beta, 0.0f), 1.0f);
    ctx = (1.0f - beta) * ctx + beta * ce;
    ctx_hist[(t * B_SZ + b) * C_DIM + d] = ctx;
  }
}

// ---------------- Kernel 2: build M as a PLAIN frag-blocked image -------------
// M[m, k] -> byte mi*2MB + (k>>5)*16384 + (m&255)*64 + (k&31)*2.  (No swizzle:
// A is consumed by direct global->VGPR frag loads, which are conflict-free and
// fully coalesced: each (fm) frag read covers a dense 1KB run.)
__global__ void build_m(const int* __restrict__ tokens,
                        const float* __restrict__ emb_act,
                        const float* __restrict__ ctx_hist,
                        char* __restrict__ Mblk) {
  const int m = blockIdx.x;
  const int tid = threadIdx.x;
  __shared__ float ctxs[C_DIM];
  __shared__ float aes[C_DIM];
  const int t = m >> 3, b = m & 7;
  const int tok = tokens[t * B_SZ + b];
  if (tid < C_DIM) {
    ctxs[tid] = ctx_hist[m * C_DIM + tid];
    aes[tid] = emb_act[tok * C_DIM + tid];
  }
  __syncthreads();
  const int c = tid >> 1;
  const int dh = (tid & 1) * 32;
  const float ae = aes[c];
  const size_t base = (size_t)(m >> 8) * 2097152 + (size_t)(m & 255) * 64;
#pragma unroll
  for (int q = 0; q < 4; ++q) {
    const int k0 = c * C_DIM + dh + q * 8;
    bf16x8 v;
#pragma unroll
    for (int jj = 0; jj < 8; ++jj) v[jj] = (__bf16)(ae * ctxs[dh + q * 8 + jj]);
    *(bf16x8*)(void*)(Mblk + base + (size_t)(k0 >> 5) * AH_BYTES +
                      (size_t)(k0 & 31) * 2) = v;
  }
}

// ---------------- Kernel 3: GEMM, phase schedule w/ split pipes ---------------
// out[512,16000] = M[512,4096] * W^T. 256x128 tile, 512 thr / 8 waves (4Mx2N).
// Per 32-k phase: A frags DIRECT global->VGPR (L2-resident image, reg dbuf,
// VMEM pipe); W via gll16 -> 4-slot f32 LDS (64KB, depth-3, LDS pipe).
// Counted waits only: steady vmcnt(18) = 3 phases x (4 A-loads + 2 W-gll16);
// prologue 10/14, tail 16/14/8. Never vmcnt(0) until the last phase.
// W LDS rows are 128B: XOR swizzle ^((col&7)<<4) stays in-row (bijective),
// inverse pre-applied on the global source (rule #21); frag reads 8-slot even.
__global__ __launch_bounds__(512, 1)
void gemm_kernel(const char* __restrict__ Ablk, const float* __restrict__ W,
                 float* __restrict__ out) {
  __shared__ __align__(16) char wlds[4][WSLOT];  // 64 KB
  const int tid = threadIdx.x;
  const int lane = tid & 63;
  const int w = tid >> 6;
  const int wm = w >> 1, wn = w & 1;  // 4M x 2N wave grid, 64x64 each
  const int lrow = lane & 15;
  const int g = lane >> 4;

  // Bijective XCD chunk swizzle (NWG=250: q=31, r=2).
  const int orig = blockIdx.x;
  const int xcd = orig & 7;
  const int wg = ((xcd < 2) ? xcd * 32 : 64 + (xcd - 2) * 31) + (orig >> 3);
  const int mi = wg & 1;
  const int n0 = (wg >> 1) * BN;

  // A: per-lane frag base (row = wm*64 + fm*16 + lrow, col-slot g)
  const char* const asb = Ablk + (size_t)mi * 2097152 +
                          (size_t)(wm * 64 + lrow) * 64 + g * 16;
  bf16x8 areg[2][4];
  auto LOAD_A = [&](int s, int h) {
    const char* ap = asb + (size_t)h * AH_BYTES;
#pragma unroll
    for (int fm = 0; fm < 4; ++fm)
      areg[s][fm] = *(const bf16x8*)(ap + fm * 1024);
  };

  // W: pre-swizzled global source, linear LDS dest.
  const char* const Wc = (const char*)W;
  const int wcol = tid >> 3;  // 0..63
  const int wkb = ((tid & 7) * 16) ^ ((wcol & 7) << 4);
  const char* const wsrc0 = Wc + (size_t)(n0 + wcol) * (K_DIM * 4) + wkb;
  const char* const wsrc1 = wsrc0 + (size_t)64 * (K_DIM * 4);
  auto STAGE_W = [&](int slot, int h) {
    gll16(wsrc0 + (size_t)h * 128, &wlds[slot][0] + tid * 16);
    gll16(wsrc1 + (size_t)h * 128, &wlds[slot][0] + 8192 + tid * 16);
  };

  f32x4 acc[4][4];
#pragma unroll
  for (int fm = 0; fm < 4; ++fm)
#pragma unroll
    for (int fn = 0; fn < 4; ++fn) acc[fm][fn] = (f32x4){0.f, 0.f, 0.f, 0.f};

  const int xo = (lrow & 7) << 4;

  auto COMPUTE = [&](int slot, int s) {
    const char* Wb = &wlds[slot][0];
    f32x4 b0[4], b1[4];
#pragma unroll
    for (int fn = 0; fn < 4; ++fn) {
      const char* cb = Wb + (wn * 64 + fn * 16 + lrow) * 128;
      b0[fn] = *(const f32x4*)(cb + ((g * 32) ^ xo));
      b1[fn] = *(const f32x4*)(cb + ((g * 32 + 16) ^ xo));
    }
    asm volatile("s_waitcnt lgkmcnt(0)" ::: "memory");
    __builtin_amdgcn_sched_barrier(0);
    __builtin_amdgcn_s_setprio(1);
#pragma unroll
    for (int fn = 0; fn < 4; ++fn) {
      bf16x8 bv;
#pragma unroll
      for (int j = 0; j < 4; ++j) {
        bv[j] = (__bf16)b0[fn][j];
        bv[4 + j] = (__bf16)b1[fn][j];
      }
#pragma unroll
      for (int fm = 0; fm < 4; ++fm)
        acc[fm][fn] = __builtin_amdgcn_mfma_f32_16x16x32_bf16(
            areg[s][fm], bv, acc[fm][fn], 0, 0, 0);
    }
    __builtin_amdgcn_s_setprio(0);
  };

#define PH_BAR() __builtin_amdgcn_s_barrier()

  // ---- prologue: A(0); W(0,1,2) ----
  LOAD_A(0, 0);
  STAGE_W(0, 0);
  STAGE_W(1, 1);
  STAGE_W(2, 2);

  // p=0
  LOAD_A(1, 1); STAGE_W(3, 3);
  asm volatile("s_waitcnt vmcnt(10)" ::: "memory");
  PH_BAR(); COMPUTE(0, 0); PH_BAR();
  // p=1
  LOAD_A(0, 2); STAGE_W(0, 4);
  asm volatile("s_waitcnt vmcnt(14)" ::: "memory");
  PH_BAR(); COMPUTE(1, 1); PH_BAR();

  // ---- main: p = 2..121 ----
#pragma unroll 1
  for (int j = 0; j < 30; ++j) {
    const int pb = 2 + j * 4;
#pragma unroll
    for (int u = 0; u < 4; ++u) {
      const int p = pb + u;
      LOAD_A((p + 1) & 1, p + 1);
      STAGE_W((p + 3) & 3, p + 3);
      asm volatile("s_waitcnt vmcnt(18)" ::: "memory");
      PH_BAR();
      COMPUTE(p & 3, p & 1);
      PH_BAR();
    }
  }

  // ---- tail: p = 122..127 ----
  LOAD_A(1, 123); STAGE_W(1, 125);
  asm volatile("s_waitcnt vmcnt(18)" ::: "memory");
  PH_BAR(); COMPUTE(2, 0); PH_BAR();
  LOAD_A(0, 124); STAGE_W(2, 126);
  asm volatile("s_waitcnt vmcnt(18)" ::: "memory");
  PH_BAR(); COMPUTE(3, 1); PH_BAR();
  LOAD_A(1, 125); STAGE_W(3, 127);
  asm volatile("s_waitcnt vmcnt(18)" ::: "memory");
  PH_BAR(); COMPUTE(0, 0); PH_BAR();
  LOAD_A(0, 126);
  asm volatile("s_waitcnt vmcnt(16)" ::: "memory");
  PH_BAR(); COMPUTE(1, 1); PH_BAR();
  LOAD_A(1, 127);
  asm volatile("s_waitcnt vmcnt(14)" ::: "memory");
  PH_BAR(); COMPUTE(2, 0); PH_BAR();
  asm volatile("s_waitcnt vmcnt(8)" ::: "memory");
  PH_BAR(); COMPUTE(3, 1);

  // ---- epilogue: C/D layout col = lane&15, row = (lane>>4)*4 + q ----
#pragma unroll
  for (int fm = 0; fm < 4; ++fm)
#pragma unroll
    for (int q = 0; q < 4; ++q) {
      const int row = mi * BM + wm * 64 + fm * 16 + g * 4 + q;
      float* po = out + (size_t)row * V_SZ + n0 + wn * 64 + lrow;
#pragma unroll
      for (int fn = 0; fn < 4; ++fn) po[fn * 16] = acc[fm][fn][q];
    }
}

extern "C" void kernel_launch(void* const* d_in, const int* in_sizes, int n_in,
                              void* d_out, int out_size, void* d_ws, size_t ws_size,
                              hipStream_t stream) {
  const int* tokens = (const int*)d_in[0];
  const float* emb_ctx = (const float*)d_in[1];
  const float* emb_act = (const float*)d_in[2];
  const float* W = (const float*)d_in[3];
  const float* beta_mult = (const float*)d_in[4];
  const float* beta_power = (const float*)d_in[5];
  float* out = (float*)d_out;

  char* Mblk = (char*)d_ws;  // 4 MB plain frag-blocked image
  float* ctx_hist = (float*)((char*)d_ws + (size_t)M_ROWS * K_DIM * 2);  // 128 KB

  ctx_kernel<<<B_SZ, C_DIM, 0, stream>>>(tokens, emb_ctx, beta_mult, beta_power,
                                         ctx_hist);
  build_m<<<M_ROWS, 128, 0, stream>>>(tokens, emb_act, ctx_hist, Mblk);
  gemm_kernel<<<NWG, 512, 0, stream>>>(Mblk, W, out);
}